// Round 4
// baseline (6306.303 us; speedup 1.0000x reference)
//
#include <hip/hip_runtime.h>

// MultiTaskLSTM: B=512, T=1024, I=64, H=256
// R4: 256 blocks = 32 batch-groups x 8 H-slices; W register-resident.
// h exchange in MFMA-fragment layout (slice ns owns A-frag kf=ns): dense
// 256B-region stores, coalesced dwordx4 frag loads. Single-RT parallel-lane
// flag poll (lanes 0-7, one load, __all). Fire-and-forget atomic flag bump.

typedef __attribute__((ext_vector_type(4))) float f32x4;
typedef __attribute__((ext_vector_type(4))) unsigned int u32x4;
typedef __attribute__((ext_vector_type(8))) short bf16x8;
typedef __attribute__((ext_vector_type(8))) unsigned short u16x8;

#define T_SZ 1024
#define I_SZ 64
#define H_SZ 256
#define KFRAGS 10
#define MROWS 16
#define NTHREADS 512
#define NBLK 256

// h buffer: frag layout [parity][bg][kf][lane][word] : u32
//   parity stride 65536 u32, group stride 2048 u32, frag stride 256 u32
#define HB_PAR 65536
#define HB_GRP 2048
#define HB_FRG 256

#define WT_FRAGS (64 * KFRAGS * 64)                 // 40960 x 16B
#define WS_BIAS_OFF  (WT_FRAGS * 16)                // 655360
#define WS_HBUF_OFF  (WS_BIAS_OFF + 4096)           // 659456
#define WS_FLAGS_OFF (WS_HBUF_OFF + 2 * HB_PAR * 4) // 1183744 (+2KB)
#define SPIN_CAP (1 << 20)

__device__ __forceinline__ unsigned short f2bf(float f) {
    unsigned int u = __builtin_bit_cast(unsigned int, f);
    unsigned int r = (u + 0x7FFFu + ((u >> 16) & 1u)) >> 16;
    return (unsigned short)r;
}
__device__ __forceinline__ float bf2f(unsigned short s) {
    unsigned int u = ((unsigned int)s) << 16;
    return __builtin_bit_cast(float, u);
}
__device__ __forceinline__ float sigm(float x) {
    return 1.0f / (1.0f + exp2f(-1.44269504f * x));
}
__device__ __forceinline__ float tanhfast(float x) {
    float e = exp2f(2.88539008f * x);
    return 1.0f - 2.0f / (e + 1.0f);
}

// W pack (same as R3): tile gt = ns*8 + w; n = lane&15;
// gate row g = (n&3)*256 + ns*32 + w*4 + (n>>2); k = kf*32 + (lane>>4)*8 + j.
__global__ void prep_kernel(const float* __restrict__ W_ih,
                            const float* __restrict__ W_hh,
                            const float* __restrict__ b_ih,
                            const float* __restrict__ b_hh,
                            unsigned short* __restrict__ Wt,
                            float* __restrict__ bias,
                            unsigned int* __restrict__ hbuf,
                            int* __restrict__ flags) {
    int gid = blockIdx.x * blockDim.x + threadIdx.x;
    if (gid < WT_FRAGS) {
        int lane = gid & 63;
        int rest = gid >> 6;
        int kf = rest % KFRAGS;
        int gt = rest / KFRAGS;
        int ns = gt >> 3, w = gt & 7;
        int n = lane & 15;
        int g = (n & 3) * 256 + ns * 32 + w * 4 + (n >> 2);
        int k0 = kf * 32 + (lane >> 4) * 8;
        u16x8 v;
        #pragma unroll
        for (int j = 0; j < 8; ++j) {
            int k = k0 + j;
            float wv = (k < H_SZ) ? W_hh[g * H_SZ + k]
                                  : W_ih[g * I_SZ + (k - H_SZ)];
            v[j] = f2bf(wv);
        }
        ((u16x8*)Wt)[gid] = v;
    } else if (gid < WT_FRAGS + 1024) {
        int j = gid - WT_FRAGS;
        bias[j] = b_ih[j] + b_hh[j];
    } else if (gid < WT_FRAGS + 1024 + 2 * HB_PAR) {
        hbuf[gid - WT_FRAGS - 1024] = 0u;
    } else if (gid < WT_FRAGS + 1024 + 2 * HB_PAR + 512) {
        flags[gid - WT_FRAGS - 1024 - 2 * HB_PAR] = 0;
    }
}

__global__ __launch_bounds__(NTHREADS)
void lstm_kernel(const float* __restrict__ x,
                 const unsigned short* __restrict__ Wt,
                 const float* __restrict__ bias,
                 unsigned int* __restrict__ hbuf,
                 int* __restrict__ flags,
                 const float* __restrict__ W_dir, const float* __restrict__ b_dir,
                 const float* __restrict__ W_q,   const float* __restrict__ b_q,
                 const float* __restrict__ W_rr,  const float* __restrict__ b_rr,
                 const float* __restrict__ W_sl,  const float* __restrict__ b_sl,
                 float* __restrict__ out)
{
    __shared__ float tr[8 * 16 * 17];               // wave-private transpose
    __shared__ unsigned int hstage[MROWS * 128];    // heads staging

    const int tid  = threadIdx.x;
    const int lane = tid & 63;
    const int wave = tid >> 6;
    const int ns   = blockIdx.x >> 5;
    const int bg   = blockIdx.x & 31;
    const int b0   = bg * MROWS;

    bf16x8 wf[KFRAGS];
    #pragma unroll
    for (int kf = 0; kf < KFRAGS; ++kf)
        wf[kf] = *(const bf16x8*)(Wt +
            ((size_t)((ns * 8 + wave) * KFRAGS + kf) * 64 + lane) * 8);

    const int er = lane & 15;
    const int hc = lane >> 4;                 // 0..3
    const int jg = ns * 32 + wave * 4 + hc;   // this thread's h column
    const float bi0 = bias[jg];
    const float bi1 = bias[256 + jg];
    const float bi2 = bias[512 + jg];
    const float bi3 = bias[768 + jg];

    float* trw = &tr[wave * (16 * 17)];
    const int n_idx = lane & 15;
    const int rb = (lane >> 4) * 4;

    const float* xbase = x + (size_t)(b0 + er) * (T_SZ * I_SZ) + hc * 8;
    int* myflag = flags + bg * 16 + ns;
    const int* fpoll = flags + bg * 16 + (lane & 7);

    // producer store slot (pairs): active lanes have hc even
    const int cp = wave * 2 + ((lane >> 5) & 1);  // colpair 0..15 (hc/2)
    unsigned int* const hw_base = hbuf + (size_t)bg * HB_GRP + ns * HB_FRG
                                  + (er + 16 * (cp >> 2)) * 4 + (cp & 3);
    const unsigned int* const hr_base = hbuf + (size_t)bg * HB_GRP + lane * 4;

    float creg = 0.0f;

    for (int t = 0; t < T_SZ; ++t) {
        const size_t rpar = (size_t)(t & 1) * HB_PAR;
        const size_t wpar = (size_t)((t + 1) & 1) * HB_PAR;

        // ---- x fragments (cached loads + pk convert) ----
        const float* xp = xbase + (size_t)t * I_SZ;
        f32x4 xa = *(const f32x4*)xp;
        f32x4 xb = *(const f32x4*)(xp + 4);
        f32x4 xc = *(const f32x4*)(xp + 32);
        f32x4 xd = *(const f32x4*)(xp + 36);
        unsigned p0, p1, p2, p3, p4, p5, p6, p7;
        asm("v_cvt_pk_bf16_f32 %0, %1, %2" : "=v"(p0) : "v"(xa[0]), "v"(xa[1]));
        asm("v_cvt_pk_bf16_f32 %0, %1, %2" : "=v"(p1) : "v"(xa[2]), "v"(xa[3]));
        asm("v_cvt_pk_bf16_f32 %0, %1, %2" : "=v"(p2) : "v"(xb[0]), "v"(xb[1]));
        asm("v_cvt_pk_bf16_f32 %0, %1, %2" : "=v"(p3) : "v"(xb[2]), "v"(xb[3]));
        asm("v_cvt_pk_bf16_f32 %0, %1, %2" : "=v"(p4) : "v"(xc[0]), "v"(xc[1]));
        asm("v_cvt_pk_bf16_f32 %0, %1, %2" : "=v"(p5) : "v"(xc[2]), "v"(xc[3]));
        asm("v_cvt_pk_bf16_f32 %0, %1, %2" : "=v"(p6) : "v"(xd[0]), "v"(xd[1]));
        asm("v_cvt_pk_bf16_f32 %0, %1, %2" : "=v"(p7) : "v"(xd[2]), "v"(xd[3]));
        u32x4 xf0u = {p0, p1, p2, p3};
        u32x4 xf1u = {p4, p5, p6, p7};

        // ---- x-part MFMAs first (off critical path) ----
        f32x4 acc = {0.0f, 0.0f, 0.0f, 0.0f};
        acc = __builtin_amdgcn_mfma_f32_16x16x32_bf16(__builtin_bit_cast(bf16x8, xf0u), wf[8], acc, 0, 0, 0);
        acc = __builtin_amdgcn_mfma_f32_16x16x32_bf16(__builtin_bit_cast(bf16x8, xf1u), wf[9], acc, 0, 0, 0);

        // ---- wait for h_t: one load covers all 8 slice flags ----
        if (t) {
            const int target = 8 * t;
            int spin = 0;
            while (true) {
                int v;
                asm volatile("global_load_dword %0, %1, off sc0 sc1\n\t"
                             "s_waitcnt vmcnt(0)"
                             : "=v"(v) : "v"(fpoll) : "memory");
                if (__all(v >= target)) break;
                if (++spin > SPIN_CAP) break;
            }
            __builtin_amdgcn_sched_barrier(0);
        }

        // ---- h fragments: 8 coalesced dwordx4 (bypass L1/L2, hit L3) ----
        u32x4 hv0, hv1, hv2, hv3, hv4, hv5, hv6, hv7;
        {
            const unsigned int* hp = hr_base + rpar;
            asm volatile("global_load_dwordx4 %0, %1, off sc0 sc1" : "=v"(hv0) : "v"(hp) : "memory");
            asm volatile("global_load_dwordx4 %0, %1, off sc0 sc1" : "=v"(hv1) : "v"(hp + HB_FRG) : "memory");
            asm volatile("global_load_dwordx4 %0, %1, off sc0 sc1" : "=v"(hv2) : "v"(hp + 2 * HB_FRG) : "memory");
            asm volatile("global_load_dwordx4 %0, %1, off sc0 sc1" : "=v"(hv3) : "v"(hp + 3 * HB_FRG) : "memory");
            asm volatile("global_load_dwordx4 %0, %1, off sc0 sc1" : "=v"(hv4) : "v"(hp + 4 * HB_FRG) : "memory");
            asm volatile("global_load_dwordx4 %0, %1, off sc0 sc1" : "=v"(hv5) : "v"(hp + 5 * HB_FRG) : "memory");
            asm volatile("global_load_dwordx4 %0, %1, off sc0 sc1" : "=v"(hv6) : "v"(hp + 6 * HB_FRG) : "memory");
            asm volatile("global_load_dwordx4 %0, %1, off sc0 sc1" : "=v"(hv7) : "v"(hp + 7 * HB_FRG) : "memory");
        }
        asm volatile("s_waitcnt vmcnt(0)" ::: "memory");
        __builtin_amdgcn_sched_barrier(0);

        // ---- 8 h MFMAs ----
        acc = __builtin_amdgcn_mfma_f32_16x16x32_bf16(__builtin_bit_cast(bf16x8, hv0), wf[0], acc, 0, 0, 0);
        acc = __builtin_amdgcn_mfma_f32_16x16x32_bf16(__builtin_bit_cast(bf16x8, hv1), wf[1], acc, 0, 0, 0);
        acc = __builtin_amdgcn_mfma_f32_16x16x32_bf16(__builtin_bit_cast(bf16x8, hv2), wf[2], acc, 0, 0, 0);
        acc = __builtin_amdgcn_mfma_f32_16x16x32_bf16(__builtin_bit_cast(bf16x8, hv3), wf[3], acc, 0, 0, 0);
        acc = __builtin_amdgcn_mfma_f32_16x16x32_bf16(__builtin_bit_cast(bf16x8, hv4), wf[4], acc, 0, 0, 0);
        acc = __builtin_amdgcn_mfma_f32_16x16x32_bf16(__builtin_bit_cast(bf16x8, hv5), wf[5], acc, 0, 0, 0);
        acc = __builtin_amdgcn_mfma_f32_16x16x32_bf16(__builtin_bit_cast(bf16x8, hv6), wf[6], acc, 0, 0, 0);
        acc = __builtin_amdgcn_mfma_f32_16x16x32_bf16(__builtin_bit_cast(bf16x8, hv7), wf[7], acc, 0, 0, 0);

        // ---- wave-local gate transpose (no barrier) ----
        #pragma unroll
        for (int q = 0; q < 4; ++q)
            trw[(rb + q) * 17 + n_idx] = acc[q];
        float gi = trw[er * 17 + hc * 4 + 0] + bi0;
        float gf = trw[er * 17 + hc * 4 + 1] + bi1;
        float gg = trw[er * 17 + hc * 4 + 2] + bi2;
        float go = trw[er * 17 + hc * 4 + 3] + bi3;

        float ii = sigm(gi), ff = sigm(gf), gG = tanhfast(gg), oo = sigm(go);
        float c = ff * creg + ii * gG;
        creg = c;
        float h = oo * tanhfast(c);

        // ---- publish h in frag layout (dense 256B region per wave) ----
        unsigned hu = (unsigned)f2bf(h);
        unsigned pj = (unsigned)__shfl_xor((int)hu, 16);
        if (!(lane & 16)) {
            unsigned v = hu | (pj << 16);
            unsigned int* sp = hw_base + wpar;
            asm volatile("global_store_dword %0, %1, off sc0 sc1" :: "v"(sp), "v"(v) : "memory");
        }
        asm volatile("s_waitcnt vmcnt(0)" ::: "memory");
        if (lane == 0)
            __hip_atomic_fetch_add(myflag, 1, __ATOMIC_RELAXED,
                                   __HIP_MEMORY_SCOPE_AGENT);
    }

    // ---- heads (slice-0 blocks) ----
    if (ns == 0) {
        {
            const int target = 8 * T_SZ;
            int spin = 0;
            while (true) {
                int v;
                asm volatile("global_load_dword %0, %1, off sc0 sc1\n\t"
                             "s_waitcnt vmcnt(0)"
                             : "=v"(v) : "v"(fpoll) : "memory");
                if (__all(v >= target)) break;
                if (++spin > SPIN_CAP) break;
            }
            __builtin_amdgcn_sched_barrier(0);
        }
        // h_T is in parity (T_SZ & 1) = 0, frag layout; unpack to hstage
        {
            int kf = tid >> 6, l = tid & 63;
            const unsigned int* hp = hbuf + (size_t)bg * HB_GRP
                                     + kf * HB_FRG + l * 4;
            u32x4 hv;
            asm volatile("global_load_dwordx4 %0, %1, off sc0 sc1" : "=v"(hv) : "v"(hp) : "memory");
            asm volatile("s_waitcnt vmcnt(0)" ::: "memory");
            __builtin_amdgcn_sched_barrier(0);
            int row = l & 15;
            int cw = kf * 16 + (l >> 4) * 4;
            hstage[row * 128 + cw + 0] = hv[0];
            hstage[row * 128 + cw + 1] = hv[1];
            hstage[row * 128 + cw + 2] = hv[2];
            hstage[row * 128 + cw + 3] = hv[3];
        }
        __syncthreads();
        if (tid < MROWS * 8) {
            int r = tid >> 3, cc = tid & 7;
            const float* wrow;
            float bb;
            if (cc == 0)      { wrow = W_dir;                 bb = b_dir[0]; }
            else if (cc <= 5) { wrow = W_q + (cc - 1) * H_SZ; bb = b_q[cc - 1]; }
            else if (cc == 6) { wrow = W_rr;                  bb = b_rr[0]; }
            else              { wrow = W_sl;                  bb = b_sl[0]; }
            float s = bb;
            for (int k = 0; k < H_SZ; ++k) {
                unsigned u = hstage[r * 128 + (k >> 1)];
                unsigned short hs = (k & 1) ? (unsigned short)(u >> 16)
                                            : (unsigned short)(u & 0xFFFF);
                s += bf2f(hs) * wrow[k];
            }
            float v = (cc == 0) ? tanhfast(s) : (cc == 7) ? sigm(s) : s;
            out[(b0 + r) * 8 + cc] = v;
        }
    }
}

extern "C" void kernel_launch(void* const* d_in, const int* in_sizes, int n_in,
                              void* d_out, int out_size, void* d_ws, size_t ws_size,
                              hipStream_t stream) {
    const float* x     = (const float*)d_in[0];
    const float* W_ih  = (const float*)d_in[1];
    const float* W_hh  = (const float*)d_in[2];
    const float* b_ih  = (const float*)d_in[3];
    const float* b_hh  = (const float*)d_in[4];
    const float* W_dir = (const float*)d_in[5];
    const float* b_dir = (const float*)d_in[6];
    const float* W_q   = (const float*)d_in[7];
    const float* b_q   = (const float*)d_in[8];
    const float* W_rr  = (const float*)d_in[9];
    const float* b_rr  = (const float*)d_in[10];
    const float* W_sl  = (const float*)d_in[11];
    const float* b_sl  = (const float*)d_in[12];

    unsigned short* Wt = (unsigned short*)d_ws;
    float* bias        = (float*)((char*)d_ws + WS_BIAS_OFF);
    unsigned int* hbuf = (unsigned int*)((char*)d_ws + WS_HBUF_OFF);
    int* flags         = (int*)((char*)d_ws + WS_FLAGS_OFF);
    float* outp        = (float*)d_out;

    // 40960 frags + 1024 bias + 131072 hbuf + 512 flags = 173568 = 678*256
    prep_kernel<<<678, 256, 0, stream>>>(W_ih, W_hh, b_ih, b_hh, Wt, bias,
                                         hbuf, flags);

    void* args[] = {(void*)&x, (void*)&Wt, (void*)&bias, (void*)&hbuf,
                    (void*)&flags, (void*)&W_dir, (void*)&b_dir, (void*)&W_q,
                    (void*)&b_q, (void*)&W_rr, (void*)&b_rr, (void*)&W_sl,
                    (void*)&b_sl, (void*)&outp};
    hipLaunchCooperativeKernel((void*)lstm_kernel, dim3(NBLK), dim3(NTHREADS),
                               args, 0, stream);
}

// Round 5
// 3175.546 us; speedup vs baseline: 1.9859x; 1.9859x over previous
//
#include <hip/hip_runtime.h>

// MultiTaskLSTM: B=512, T=1024, I=64, H=256
// R5: 256 blocks = 32 batch-groups x 8 H-slices; W register-resident; h
// exchange in MFMA-fragment layout at L3 (sc0 sc1). vs R4:
//  - flags: ONE per block on its OWN 64B line, plain store of t+1 (replaces
//    64 same-line atomic RMWs/group/step -> removes L3 RMW serialization)
//  - ordering: per-wave counted vmcnt(4) (h-store ack) -> raw s_barrier
//    (no counter drain) -> tid0 flag store
//  - x_{t+1} prefetch issued between h-store and its ack (latency hidden)
//  - MFMA chain split into two accumulators

typedef __attribute__((ext_vector_type(4))) float f32x4;
typedef __attribute__((ext_vector_type(4))) unsigned int u32x4;
typedef __attribute__((ext_vector_type(8))) short bf16x8;
typedef __attribute__((ext_vector_type(8))) unsigned short u16x8;

#define T_SZ 1024
#define I_SZ 64
#define H_SZ 256
#define KFRAGS 10
#define MROWS 16
#define NTHREADS 512
#define NBLK 256

// h buffer: frag layout [parity][bg][kf][lane][word] : u32
#define HB_PAR 65536
#define HB_GRP 2048
#define HB_FRG 256

#define FLAG_STRIDE 16                              // u32; 64B per flag line
#define NFLAG (32 * 8 * FLAG_STRIDE)                // 4096 u32

#define WT_FRAGS (64 * KFRAGS * 64)                 // 40960 x 16B
#define WS_BIAS_OFF  (WT_FRAGS * 16)                // 655360
#define WS_HBUF_OFF  (WS_BIAS_OFF + 4096)           // 659456
#define WS_FLAGS_OFF (WS_HBUF_OFF + 2 * HB_PAR * 4) // + 512KB
#define SPIN_CAP (1 << 20)

__device__ __forceinline__ unsigned short f2bf(float f) {
    unsigned int u = __builtin_bit_cast(unsigned int, f);
    unsigned int r = (u + 0x7FFFu + ((u >> 16) & 1u)) >> 16;
    return (unsigned short)r;
}
__device__ __forceinline__ float bf2f(unsigned short s) {
    unsigned int u = ((unsigned int)s) << 16;
    return __builtin_bit_cast(float, u);
}
__device__ __forceinline__ float sigm(float x) {
    return 1.0f / (1.0f + exp2f(-1.44269504f * x));
}
__device__ __forceinline__ float tanhfast(float x) {
    float e = exp2f(2.88539008f * x);
    return 1.0f - 2.0f / (e + 1.0f);
}

// W pack: tile gt = ns*8 + w; n = lane&15;
// gate row g = (n&3)*256 + ns*32 + w*4 + (n>>2); k = kf*32 + (lane>>4)*8 + j.
__global__ void prep_kernel(const float* __restrict__ W_ih,
                            const float* __restrict__ W_hh,
                            const float* __restrict__ b_ih,
                            const float* __restrict__ b_hh,
                            unsigned short* __restrict__ Wt,
                            float* __restrict__ bias,
                            unsigned int* __restrict__ hbuf,
                            int* __restrict__ flags) {
    int gid = blockIdx.x * blockDim.x + threadIdx.x;
    if (gid < WT_FRAGS) {
        int lane = gid & 63;
        int rest = gid >> 6;
        int kf = rest % KFRAGS;
        int gt = rest / KFRAGS;
        int ns = gt >> 3, w = gt & 7;
        int n = lane & 15;
        int g = (n & 3) * 256 + ns * 32 + w * 4 + (n >> 2);
        int k0 = kf * 32 + (lane >> 4) * 8;
        u16x8 v;
        #pragma unroll
        for (int j = 0; j < 8; ++j) {
            int k = k0 + j;
            float wv = (k < H_SZ) ? W_hh[g * H_SZ + k]
                                  : W_ih[g * I_SZ + (k - H_SZ)];
            v[j] = f2bf(wv);
        }
        ((u16x8*)Wt)[gid] = v;
    } else if (gid < WT_FRAGS + 1024) {
        int j = gid - WT_FRAGS;
        bias[j] = b_ih[j] + b_hh[j];
    } else if (gid < WT_FRAGS + 1024 + 2 * HB_PAR) {
        hbuf[gid - WT_FRAGS - 1024] = 0u;
    } else if (gid < WT_FRAGS + 1024 + 2 * HB_PAR + NFLAG) {
        flags[gid - WT_FRAGS - 1024 - 2 * HB_PAR] = 0;
    }
}

__global__ __launch_bounds__(NTHREADS)
void lstm_kernel(const float* __restrict__ x,
                 const unsigned short* __restrict__ Wt,
                 const float* __restrict__ bias,
                 unsigned int* __restrict__ hbuf,
                 int* __restrict__ flags,
                 const float* __restrict__ W_dir, const float* __restrict__ b_dir,
                 const float* __restrict__ W_q,   const float* __restrict__ b_q,
                 const float* __restrict__ W_rr,  const float* __restrict__ b_rr,
                 const float* __restrict__ W_sl,  const float* __restrict__ b_sl,
                 float* __restrict__ out)
{
    __shared__ float tr[8 * 16 * 17];
    __shared__ unsigned int hstage[MROWS * 128];

    const int tid  = threadIdx.x;
    const int lane = tid & 63;
    const int wave = tid >> 6;
    const int ns   = blockIdx.x >> 5;
    const int bg   = blockIdx.x & 31;
    const int b0   = bg * MROWS;

    bf16x8 wf[KFRAGS];
    #pragma unroll
    for (int kf = 0; kf < KFRAGS; ++kf)
        wf[kf] = *(const bf16x8*)(Wt +
            ((size_t)((ns * 8 + wave) * KFRAGS + kf) * 64 + lane) * 8);

    const int er = lane & 15;
    const int hc = lane >> 4;
    const int jg = ns * 32 + wave * 4 + hc;
    const float bi0 = bias[jg];
    const float bi1 = bias[256 + jg];
    const float bi2 = bias[512 + jg];
    const float bi3 = bias[768 + jg];

    float* trw = &tr[wave * (16 * 17)];
    const int n_idx = lane & 15;
    const int rb = (lane >> 4) * 4;

    const float* xbase = x + (size_t)(b0 + er) * (T_SZ * I_SZ) + hc * 8;
    int* myflag = flags + (bg * 8 + ns) * FLAG_STRIDE;
    const int* fpoll = flags + (bg * 8 + (lane & 7)) * FLAG_STRIDE;

    const int cp = wave * 2 + ((lane >> 5) & 1);
    unsigned int* const hw_base = hbuf + (size_t)bg * HB_GRP + ns * HB_FRG
                                  + (er + 16 * (cp >> 2)) * 4 + (cp & 3);
    const unsigned int* const hr_base = hbuf + (size_t)bg * HB_GRP + lane * 4;

    float creg = 0.0f;

    // ---- preload + convert x_0 ----
    f32x4 xa = *(const f32x4*)xbase;
    f32x4 xb = *(const f32x4*)(xbase + 4);
    f32x4 xc = *(const f32x4*)(xbase + 32);
    f32x4 xd = *(const f32x4*)(xbase + 36);
    u32x4 xf0u, xf1u;
    {
        unsigned p0, p1, p2, p3, p4, p5, p6, p7;
        asm("v_cvt_pk_bf16_f32 %0, %1, %2" : "=v"(p0) : "v"(xa[0]), "v"(xa[1]));
        asm("v_cvt_pk_bf16_f32 %0, %1, %2" : "=v"(p1) : "v"(xa[2]), "v"(xa[3]));
        asm("v_cvt_pk_bf16_f32 %0, %1, %2" : "=v"(p2) : "v"(xb[0]), "v"(xb[1]));
        asm("v_cvt_pk_bf16_f32 %0, %1, %2" : "=v"(p3) : "v"(xb[2]), "v"(xb[3]));
        asm("v_cvt_pk_bf16_f32 %0, %1, %2" : "=v"(p4) : "v"(xc[0]), "v"(xc[1]));
        asm("v_cvt_pk_bf16_f32 %0, %1, %2" : "=v"(p5) : "v"(xc[2]), "v"(xc[3]));
        asm("v_cvt_pk_bf16_f32 %0, %1, %2" : "=v"(p6) : "v"(xd[0]), "v"(xd[1]));
        asm("v_cvt_pk_bf16_f32 %0, %1, %2" : "=v"(p7) : "v"(xd[2]), "v"(xd[3]));
        xf0u = (u32x4){p0, p1, p2, p3};
        xf1u = (u32x4){p4, p5, p6, p7};
    }

    for (int t = 0; t < T_SZ; ++t) {
        const size_t rpar = (size_t)(t & 1) * HB_PAR;
        const size_t wpar = (size_t)((t + 1) & 1) * HB_PAR;

        // ---- wait for h_t (lanes 0-7, one load covers 8 padded flags) ----
        if (t) {
            int spin = 0;
            while (true) {
                int v;
                asm volatile("global_load_dword %0, %1, off sc0 sc1\n\t"
                             "s_waitcnt vmcnt(0)"
                             : "=v"(v) : "v"(fpoll) : "memory");
                if (__all(v >= t)) break;
                if (++spin > SPIN_CAP) break;
            }
            __builtin_amdgcn_sched_barrier(0);
        }

        // ---- h fragments: 8 coalesced dwordx4 (L3) ----
        u32x4 hv0, hv1, hv2, hv3, hv4, hv5, hv6, hv7;
        {
            const unsigned int* hp = hr_base + rpar;
            asm volatile("global_load_dwordx4 %0, %1, off sc0 sc1" : "=v"(hv0) : "v"(hp) : "memory");
            asm volatile("global_load_dwordx4 %0, %1, off sc0 sc1" : "=v"(hv1) : "v"(hp + HB_FRG) : "memory");
            asm volatile("global_load_dwordx4 %0, %1, off sc0 sc1" : "=v"(hv2) : "v"(hp + 2 * HB_FRG) : "memory");
            asm volatile("global_load_dwordx4 %0, %1, off sc0 sc1" : "=v"(hv3) : "v"(hp + 3 * HB_FRG) : "memory");
            asm volatile("global_load_dwordx4 %0, %1, off sc0 sc1" : "=v"(hv4) : "v"(hp + 4 * HB_FRG) : "memory");
            asm volatile("global_load_dwordx4 %0, %1, off sc0 sc1" : "=v"(hv5) : "v"(hp + 5 * HB_FRG) : "memory");
            asm volatile("global_load_dwordx4 %0, %1, off sc0 sc1" : "=v"(hv6) : "v"(hp + 6 * HB_FRG) : "memory");
            asm volatile("global_load_dwordx4 %0, %1, off sc0 sc1" : "=v"(hv7) : "v"(hp + 7 * HB_FRG) : "memory");
        }
        // x-part MFMAs can issue while h loads are in flight
        f32x4 accA = {0.0f, 0.0f, 0.0f, 0.0f};
        f32x4 accB = {0.0f, 0.0f, 0.0f, 0.0f};
        accA = __builtin_amdgcn_mfma_f32_16x16x32_bf16(__builtin_bit_cast(bf16x8, xf0u), wf[8], accA, 0, 0, 0);
        accB = __builtin_amdgcn_mfma_f32_16x16x32_bf16(__builtin_bit_cast(bf16x8, xf1u), wf[9], accB, 0, 0, 0);
        asm volatile("s_waitcnt vmcnt(0)" ::: "memory");
        __builtin_amdgcn_sched_barrier(0);

        // ---- 8 h MFMAs, two chains ----
        accA = __builtin_amdgcn_mfma_f32_16x16x32_bf16(__builtin_bit_cast(bf16x8, hv0), wf[0], accA, 0, 0, 0);
        accB = __builtin_amdgcn_mfma_f32_16x16x32_bf16(__builtin_bit_cast(bf16x8, hv1), wf[1], accB, 0, 0, 0);
        accA = __builtin_amdgcn_mfma_f32_16x16x32_bf16(__builtin_bit_cast(bf16x8, hv2), wf[2], accA, 0, 0, 0);
        accB = __builtin_amdgcn_mfma_f32_16x16x32_bf16(__builtin_bit_cast(bf16x8, hv3), wf[3], accB, 0, 0, 0);
        accA = __builtin_amdgcn_mfma_f32_16x16x32_bf16(__builtin_bit_cast(bf16x8, hv4), wf[4], accA, 0, 0, 0);
        accB = __builtin_amdgcn_mfma_f32_16x16x32_bf16(__builtin_bit_cast(bf16x8, hv5), wf[5], accB, 0, 0, 0);
        accA = __builtin_amdgcn_mfma_f32_16x16x32_bf16(__builtin_bit_cast(bf16x8, hv6), wf[6], accA, 0, 0, 0);
        accB = __builtin_amdgcn_mfma_f32_16x16x32_bf16(__builtin_bit_cast(bf16x8, hv7), wf[7], accB, 0, 0, 0);
        f32x4 acc = accA + accB;

        // ---- wave-local gate transpose ----
        #pragma unroll
        for (int q = 0; q < 4; ++q)
            trw[(rb + q) * 17 + n_idx] = acc[q];
        float gi = trw[er * 17 + hc * 4 + 0] + bi0;
        float gf = trw[er * 17 + hc * 4 + 1] + bi1;
        float gg = trw[er * 17 + hc * 4 + 2] + bi2;
        float go = trw[er * 17 + hc * 4 + 3] + bi3;

        float ii = sigm(gi), ff = sigm(gf), gG = tanhfast(gg), oo = sigm(go);
        float c = ff * creg + ii * gG;
        creg = c;
        float h = oo * tanhfast(c);

        // ---- publish h (frag layout) ----
        unsigned hu = (unsigned)f2bf(h);
        unsigned pj = (unsigned)__shfl_xor((int)hu, 16);
        if (!(lane & 16)) {
            unsigned v = hu | (pj << 16);
            unsigned int* sp = hw_base + wpar;
            asm volatile("global_store_dword %0, %1, off sc0 sc1" :: "v"(sp), "v"(v) : "memory");
        }

        // ---- x_{t+1} prefetch issued under the store-ack window ----
        {
            const float* xp = xbase + (size_t)((t + 1 < T_SZ) ? t + 1 : t) * I_SZ;
            asm volatile("global_load_dwordx4 %0, %1, off" : "=v"(xa) : "v"(xp) : "memory");
            asm volatile("global_load_dwordx4 %0, %1, off" : "=v"(xb) : "v"(xp + 4) : "memory");
            asm volatile("global_load_dwordx4 %0, %1, off" : "=v"(xc) : "v"(xp + 32) : "memory");
            asm volatile("global_load_dwordx4 %0, %1, off" : "=v"(xd) : "v"(xp + 36) : "memory");
        }
        asm volatile("s_waitcnt vmcnt(4)" ::: "memory");   // h-store ack'd
        __builtin_amdgcn_s_barrier();                       // no counter drain
        if (tid == 0) {
            int fv = t + 1;
            asm volatile("global_store_dword %0, %1, off sc0 sc1" :: "v"(myflag), "v"(fv) : "memory");
        }
        asm volatile("s_waitcnt vmcnt(0)" ::: "memory");    // x loads done
        __builtin_amdgcn_sched_barrier(0);
        {
            unsigned p0, p1, p2, p3, p4, p5, p6, p7;
            asm("v_cvt_pk_bf16_f32 %0, %1, %2" : "=v"(p0) : "v"(xa[0]), "v"(xa[1]));
            asm("v_cvt_pk_bf16_f32 %0, %1, %2" : "=v"(p1) : "v"(xa[2]), "v"(xa[3]));
            asm("v_cvt_pk_bf16_f32 %0, %1, %2" : "=v"(p2) : "v"(xb[0]), "v"(xb[1]));
            asm("v_cvt_pk_bf16_f32 %0, %1, %2" : "=v"(p3) : "v"(xb[2]), "v"(xb[3]));
            asm("v_cvt_pk_bf16_f32 %0, %1, %2" : "=v"(p4) : "v"(xc[0]), "v"(xc[1]));
            asm("v_cvt_pk_bf16_f32 %0, %1, %2" : "=v"(p5) : "v"(xc[2]), "v"(xc[3]));
            asm("v_cvt_pk_bf16_f32 %0, %1, %2" : "=v"(p6) : "v"(xd[0]), "v"(xd[1]));
            asm("v_cvt_pk_bf16_f32 %0, %1, %2" : "=v"(p7) : "v"(xd[2]), "v"(xd[3]));
            xf0u = (u32x4){p0, p1, p2, p3};
            xf1u = (u32x4){p4, p5, p6, p7};
        }
    }

    // ---- heads (slice-0 blocks) ----
    if (ns == 0) {
        {
            int spin = 0;
            while (true) {
                int v;
                asm volatile("global_load_dword %0, %1, off sc0 sc1\n\t"
                             "s_waitcnt vmcnt(0)"
                             : "=v"(v) : "v"(fpoll) : "memory");
                if (__all(v >= T_SZ)) break;
                if (++spin > SPIN_CAP) break;
            }
            __builtin_amdgcn_sched_barrier(0);
        }
        {
            int kf = tid >> 6, l = tid & 63;
            const unsigned int* hp = hbuf + (size_t)bg * HB_GRP
                                     + kf * HB_FRG + l * 4;
            u32x4 hv;
            asm volatile("global_load_dwordx4 %0, %1, off sc0 sc1" : "=v"(hv) : "v"(hp) : "memory");
            asm volatile("s_waitcnt vmcnt(0)" ::: "memory");
            __builtin_amdgcn_sched_barrier(0);
            int row = l & 15;
            int cw = kf * 16 + (l >> 4) * 4;
            hstage[row * 128 + cw + 0] = hv[0];
            hstage[row * 128 + cw + 1] = hv[1];
            hstage[row * 128 + cw + 2] = hv[2];
            hstage[row * 128 + cw + 3] = hv[3];
        }
        __syncthreads();
        if (tid < MROWS * 8) {
            int r = tid >> 3, cc = tid & 7;
            const float* wrow;
            float bb;
            if (cc == 0)      { wrow = W_dir;                 bb = b_dir[0]; }
            else if (cc <= 5) { wrow = W_q + (cc - 1) * H_SZ; bb = b_q[cc - 1]; }
            else if (cc == 6) { wrow = W_rr;                  bb = b_rr[0]; }
            else              { wrow = W_sl;                  bb = b_sl[0]; }
            float s = bb;
            for (int k = 0; k < H_SZ; ++k) {
                unsigned u = hstage[r * 128 + (k >> 1)];
                unsigned short hs = (k & 1) ? (unsigned short)(u >> 16)
                                            : (unsigned short)(u & 0xFFFF);
                s += bf2f(hs) * wrow[k];
            }
            float v = (cc == 0) ? tanhfast(s) : (cc == 7) ? sigm(s) : s;
            out[(b0 + r) * 8 + cc] = v;
        }
    }
}

extern "C" void kernel_launch(void* const* d_in, const int* in_sizes, int n_in,
                              void* d_out, int out_size, void* d_ws, size_t ws_size,
                              hipStream_t stream) {
    const float* x     = (const float*)d_in[0];
    const float* W_ih  = (const float*)d_in[1];
    const float* W_hh  = (const float*)d_in[2];
    const float* b_ih  = (const float*)d_in[3];
    const float* b_hh  = (const float*)d_in[4];
    const float* W_dir = (const float*)d_in[5];
    const float* b_dir = (const float*)d_in[6];
    const float* W_q   = (const float*)d_in[7];
    const float* b_q   = (const float*)d_in[8];
    const float* W_rr  = (const float*)d_in[9];
    const float* b_rr  = (const float*)d_in[10];
    const float* W_sl  = (const float*)d_in[11];
    const float* b_sl  = (const float*)d_in[12];

    unsigned short* Wt = (unsigned short*)d_ws;
    float* bias        = (float*)((char*)d_ws + WS_BIAS_OFF);
    unsigned int* hbuf = (unsigned int*)((char*)d_ws + WS_HBUF_OFF);
    int* flags         = (int*)((char*)d_ws + WS_FLAGS_OFF);
    float* outp        = (float*)d_out;

    // 40960 frags + 1024 bias + 131072 hbuf + 4096 flags = 177152 = 692*256
    prep_kernel<<<692, 256, 0, stream>>>(W_ih, W_hh, b_ih, b_hh, Wt, bias,
                                         hbuf, flags);

    void* args[] = {(void*)&x, (void*)&Wt, (void*)&bias, (void*)&hbuf,
                    (void*)&flags, (void*)&W_dir, (void*)&b_dir, (void*)&W_q,
                    (void*)&b_q, (void*)&W_rr, (void*)&b_rr, (void*)&W_sl,
                    (void*)&b_sl, (void*)&outp};
    hipLaunchCooperativeKernel((void*)lstm_kernel, dim3(NBLK), dim3(NTHREADS),
                               args, 0, stream);
}

// Round 9
// 3059.886 us; speedup vs baseline: 2.0610x; 1.0378x over previous
//
#include <hip/hip_runtime.h>

// MultiTaskLSTM: B=512, T=1024, I=64, H=256
// R9: recover R5's PROVEN exchange protocol exactly (sc0sc1 stores, poll-
// detect-THEN-fetch, vmcnt(4) store-ack -> raw s_barrier -> tid0 flag store,
// per-wave redundant frag loads, no LDS h staging). Only change vs R5:
// group geometry 8 slices -> 4 slices (128 blocks). Each block owns 64 h-cols
// (256 gate rows); per wave 2 output tiles (W = 80 VGPR, register-resident).
// Halves L3 h-read traffic and flag fan-in (straggler max over 4 not 8).

typedef __attribute__((ext_vector_type(4))) float f32x4;
typedef __attribute__((ext_vector_type(4))) unsigned int u32x4;
typedef __attribute__((ext_vector_type(8))) short bf16x8;
typedef __attribute__((ext_vector_type(8))) unsigned short u16x8;

#define T_SZ 1024
#define I_SZ 64
#define H_SZ 256
#define KFRAGS 10
#define MROWS 16
#define NTHREADS 512
#define NBLK 128           // 32 groups x 4 slices

// h buffer: frag layout [parity][bg][kf][lane][word] : u32 (unchanged)
#define HB_PAR 65536
#define HB_GRP 2048
#define HB_FRG 256

#define FLAG_STRIDE 64                              // u32; 256B per flag line
#define NFLAG (32 * 4 * FLAG_STRIDE)                // 8192 u32

#define WT_FRAGS (64 * KFRAGS * 64)                 // 40960 x 16B (same size)
#define WS_BIAS_OFF  (WT_FRAGS * 16)                // 655360
#define WS_HBUF_OFF  (WS_BIAS_OFF + 4096)
#define WS_FLAGS_OFF (WS_HBUF_OFF + 2 * HB_PAR * 4)
#define SPIN_CAP (1 << 20)

__device__ __forceinline__ unsigned short f2bf(float f) {
    unsigned int u = __builtin_bit_cast(unsigned int, f);
    unsigned int r = (u + 0x7FFFu + ((u >> 16) & 1u)) >> 16;
    return (unsigned short)r;
}
__device__ __forceinline__ float bf2f(unsigned short s) {
    unsigned int u = ((unsigned int)s) << 16;
    return __builtin_bit_cast(float, u);
}
__device__ __forceinline__ float sigm(float x) {
    return 1.0f / (1.0f + exp2f(-1.44269504f * x));
}
__device__ __forceinline__ float tanhfast(float x) {
    float e = exp2f(2.88539008f * x);
    return 1.0f - 2.0f / (e + 1.0f);
}

// W pack for 4-slice tiling. Frag id = ((ns*8+w)*2+t)*10 + kf, lane:
//   n = lane&15 -> gate = n&3, hcol-in-tile = n>>2
//   gate row g = (n&3)*256 + ns*64 + w*8 + t*4 + (n>>2)
//   k = kf*32 + (lane>>4)*8 + j   (k<256 -> W_hh, else W_ih)
__global__ void prep_kernel(const float* __restrict__ W_ih,
                            const float* __restrict__ W_hh,
                            const float* __restrict__ b_ih,
                            const float* __restrict__ b_hh,
                            unsigned short* __restrict__ Wt,
                            float* __restrict__ bias,
                            unsigned int* __restrict__ hbuf,
                            int* __restrict__ flags) {
    int gid = blockIdx.x * blockDim.x + threadIdx.x;
    if (gid < WT_FRAGS) {
        int lane = gid & 63;
        int rest = gid >> 6;               // 0..639
        int kf = rest % KFRAGS;
        int tileid = rest / KFRAGS;        // 0..63
        int t  = tileid & 1;
        int w  = (tileid >> 1) & 7;
        int ns = tileid >> 4;              // 0..3
        int n = lane & 15;
        int g = (n & 3) * 256 + ns * 64 + w * 8 + t * 4 + (n >> 2);
        int k0 = kf * 32 + (lane >> 4) * 8;
        u16x8 v;
        #pragma unroll
        for (int j = 0; j < 8; ++j) {
            int k = k0 + j;
            float wv = (k < H_SZ) ? W_hh[g * H_SZ + k]
                                  : W_ih[g * I_SZ + (k - H_SZ)];
            v[j] = f2bf(wv);
        }
        ((u16x8*)Wt)[gid] = v;
    } else if (gid < WT_FRAGS + 1024) {
        int j = gid - WT_FRAGS;
        bias[j] = b_ih[j] + b_hh[j];
    } else if (gid < WT_FRAGS + 1024 + 2 * HB_PAR) {
        hbuf[gid - WT_FRAGS - 1024] = 0u;
    } else if (gid < WT_FRAGS + 1024 + 2 * HB_PAR + NFLAG) {
        flags[gid - WT_FRAGS - 1024 - 2 * HB_PAR] = 0;
    }
}

__global__ __launch_bounds__(NTHREADS)
void lstm_kernel(const float* __restrict__ x,
                 const unsigned short* __restrict__ Wt,
                 const float* __restrict__ bias,
                 unsigned int* __restrict__ hbuf,
                 int* __restrict__ flags,
                 const float* __restrict__ W_dir, const float* __restrict__ b_dir,
                 const float* __restrict__ W_q,   const float* __restrict__ b_q,
                 const float* __restrict__ W_rr,  const float* __restrict__ b_rr,
                 const float* __restrict__ W_sl,  const float* __restrict__ b_sl,
                 float* __restrict__ out)
{
    __shared__ float tr[16 * 16 * 17];              // 2 tiles per wave
    __shared__ unsigned int hstage[MROWS * 128];

    const int tid  = threadIdx.x;
    const int lane = tid & 63;
    const int wave = tid >> 6;
    const int ns   = blockIdx.x >> 5;     // 0..3
    const int bg   = blockIdx.x & 31;
    const int b0   = bg * MROWS;

    // register-resident W fragments: 2 tiles x 10 frags (80 VGPR)
    bf16x8 wf0[KFRAGS], wf1[KFRAGS];
    #pragma unroll
    for (int kf = 0; kf < KFRAGS; ++kf) {
        wf0[kf] = *(const bf16x8*)(Wt +
            ((size_t)((((ns * 8 + wave) * 2 + 0) * KFRAGS) + kf) * 64 + lane) * 8);
        wf1[kf] = *(const bf16x8*)(Wt +
            ((size_t)((((ns * 8 + wave) * 2 + 1) * KFRAGS) + kf) * 64 + lane) * 8);
    }

    const int er = lane & 15;
    const int hc = lane >> 4;                         // 0..3
    const int jg0 = ns * 64 + wave * 8 + 0 * 4 + hc;  // tile-0 h col
    const int jg1 = ns * 64 + wave * 8 + 1 * 4 + hc;  // tile-1 h col
    const float b00 = bias[jg0],       b01 = bias[256 + jg0];
    const float b02 = bias[512 + jg0], b03 = bias[768 + jg0];
    const float b10 = bias[jg1],       b11 = bias[256 + jg1];
    const float b12 = bias[512 + jg1], b13 = bias[768 + jg1];

    float* trw0 = &tr[(wave * 2 + 0) * (16 * 17)];
    float* trw1 = &tr[(wave * 2 + 1) * (16 * 17)];
    const int n_idx = lane & 15;
    const int rb = (lane >> 4) * 4;

    const float* xbase = x + (size_t)(b0 + er) * (T_SZ * I_SZ) + hc * 8;
    int* myflag = flags + (bg * 4 + ns) * FLAG_STRIDE;
    const int* fpoll = flags + (bg * 4 + (lane & 3)) * FLAG_STRIDE;

    // publish addresses (frag layout). Global col-pair P = ns*32 + w*4 + t*2
    //  + ((lane>>5)&1); word addr = bg*HB_GRP + (P>>4)*HB_FRG
    //  + (er + 16*((P>>2)&3))*4 + (P&3).
    const int P0 = ns * 32 + wave * 4 + 0 * 2 + ((lane >> 5) & 1);
    const int P1 = ns * 32 + wave * 4 + 1 * 2 + ((lane >> 5) & 1);
    unsigned int* const hw_base0 = hbuf + (size_t)bg * HB_GRP
        + (P0 >> 4) * HB_FRG + (er + 16 * ((P0 >> 2) & 3)) * 4 + (P0 & 3);
    unsigned int* const hw_base1 = hbuf + (size_t)bg * HB_GRP
        + (P1 >> 4) * HB_FRG + (er + 16 * ((P1 >> 2) & 3)) * 4 + (P1 & 3);
    const unsigned int* const hr_base = hbuf + (size_t)bg * HB_GRP + lane * 4;

    float creg0 = 0.0f, creg1 = 0.0f;

    // preload + convert x_0
    f32x4 xa = *(const f32x4*)xbase;
    f32x4 xb = *(const f32x4*)(xbase + 4);
    f32x4 xc = *(const f32x4*)(xbase + 32);
    f32x4 xd = *(const f32x4*)(xbase + 36);
    u32x4 xf0u, xf1u;
    {
        unsigned p0, p1, p2, p3, p4, p5, p6, p7;
        asm("v_cvt_pk_bf16_f32 %0, %1, %2" : "=v"(p0) : "v"(xa[0]), "v"(xa[1]));
        asm("v_cvt_pk_bf16_f32 %0, %1, %2" : "=v"(p1) : "v"(xa[2]), "v"(xa[3]));
        asm("v_cvt_pk_bf16_f32 %0, %1, %2" : "=v"(p2) : "v"(xb[0]), "v"(xb[1]));
        asm("v_cvt_pk_bf16_f32 %0, %1, %2" : "=v"(p3) : "v"(xb[2]), "v"(xb[3]));
        asm("v_cvt_pk_bf16_f32 %0, %1, %2" : "=v"(p4) : "v"(xc[0]), "v"(xc[1]));
        asm("v_cvt_pk_bf16_f32 %0, %1, %2" : "=v"(p5) : "v"(xc[2]), "v"(xc[3]));
        asm("v_cvt_pk_bf16_f32 %0, %1, %2" : "=v"(p6) : "v"(xd[0]), "v"(xd[1]));
        asm("v_cvt_pk_bf16_f32 %0, %1, %2" : "=v"(p7) : "v"(xd[2]), "v"(xd[3]));
        xf0u = (u32x4){p0, p1, p2, p3};
        xf1u = (u32x4){p4, p5, p6, p7};
    }

    for (int t = 0; t < T_SZ; ++t) {
        const size_t rpar = (size_t)(t & 1) * HB_PAR;
        const size_t wpar = (size_t)((t + 1) & 1) * HB_PAR;

        // ---- wait for h_t: lanes cover the 4 padded flag lines (R5 protocol:
        // detect STRICTLY precedes data fetch) ----
        if (t) {
            int spin = 0;
            while (true) {
                int v;
                asm volatile("global_load_dword %0, %1, off sc0 sc1\n\t"
                             "s_waitcnt vmcnt(0)"
                             : "=v"(v) : "v"(fpoll) : "memory");
                if (__all(v >= t)) break;
                if (++spin > SPIN_CAP) break;
            }
            __builtin_amdgcn_sched_barrier(0);
        }

        // ---- h fragments: 8 coalesced dwordx4 (L3) ----
        u32x4 hv0, hv1, hv2, hv3, hv4, hv5, hv6, hv7;
        {
            const unsigned int* hp = hr_base + rpar;
            asm volatile("global_load_dwordx4 %0, %1, off sc0 sc1" : "=v"(hv0) : "v"(hp) : "memory");
            asm volatile("global_load_dwordx4 %0, %1, off sc0 sc1" : "=v"(hv1) : "v"(hp + HB_FRG) : "memory");
            asm volatile("global_load_dwordx4 %0, %1, off sc0 sc1" : "=v"(hv2) : "v"(hp + 2 * HB_FRG) : "memory");
            asm volatile("global_load_dwordx4 %0, %1, off sc0 sc1" : "=v"(hv3) : "v"(hp + 3 * HB_FRG) : "memory");
            asm volatile("global_load_dwordx4 %0, %1, off sc0 sc1" : "=v"(hv4) : "v"(hp + 4 * HB_FRG) : "memory");
            asm volatile("global_load_dwordx4 %0, %1, off sc0 sc1" : "=v"(hv5) : "v"(hp + 5 * HB_FRG) : "memory");
            asm volatile("global_load_dwordx4 %0, %1, off sc0 sc1" : "=v"(hv6) : "v"(hp + 6 * HB_FRG) : "memory");
            asm volatile("global_load_dwordx4 %0, %1, off sc0 sc1" : "=v"(hv7) : "v"(hp + 7 * HB_FRG) : "memory");
        }
        // x-part MFMAs issue while h loads are in flight
        f32x4 acc0 = {0.0f, 0.0f, 0.0f, 0.0f};
        f32x4 acc1 = {0.0f, 0.0f, 0.0f, 0.0f};
        acc0 = __builtin_amdgcn_mfma_f32_16x16x32_bf16(__builtin_bit_cast(bf16x8, xf0u), wf0[8], acc0, 0, 0, 0);
        acc1 = __builtin_amdgcn_mfma_f32_16x16x32_bf16(__builtin_bit_cast(bf16x8, xf0u), wf1[8], acc1, 0, 0, 0);
        acc0 = __builtin_amdgcn_mfma_f32_16x16x32_bf16(__builtin_bit_cast(bf16x8, xf1u), wf0[9], acc0, 0, 0, 0);
        acc1 = __builtin_amdgcn_mfma_f32_16x16x32_bf16(__builtin_bit_cast(bf16x8, xf1u), wf1[9], acc1, 0, 0, 0);
        asm volatile("s_waitcnt vmcnt(0)" ::: "memory");
        __builtin_amdgcn_sched_barrier(0);

        // ---- 16 h MFMAs (2 tiles, independent chains) ----
        acc0 = __builtin_amdgcn_mfma_f32_16x16x32_bf16(__builtin_bit_cast(bf16x8, hv0), wf0[0], acc0, 0, 0, 0);
        acc1 = __builtin_amdgcn_mfma_f32_16x16x32_bf16(__builtin_bit_cast(bf16x8, hv0), wf1[0], acc1, 0, 0, 0);
        acc0 = __builtin_amdgcn_mfma_f32_16x16x32_bf16(__builtin_bit_cast(bf16x8, hv1), wf0[1], acc0, 0, 0, 0);
        acc1 = __builtin_amdgcn_mfma_f32_16x16x32_bf16(__builtin_bit_cast(bf16x8, hv1), wf1[1], acc1, 0, 0, 0);
        acc0 = __builtin_amdgcn_mfma_f32_16x16x32_bf16(__builtin_bit_cast(bf16x8, hv2), wf0[2], acc0, 0, 0, 0);
        acc1 = __builtin_amdgcn_mfma_f32_16x16x32_bf16(__builtin_bit_cast(bf16x8, hv2), wf1[2], acc1, 0, 0, 0);
        acc0 = __builtin_amdgcn_mfma_f32_16x16x32_bf16(__builtin_bit_cast(bf16x8, hv3), wf0[3], acc0, 0, 0, 0);
        acc1 = __builtin_amdgcn_mfma_f32_16x16x32_bf16(__builtin_bit_cast(bf16x8, hv3), wf1[3], acc1, 0, 0, 0);
        acc0 = __builtin_amdgcn_mfma_f32_16x16x32_bf16(__builtin_bit_cast(bf16x8, hv4), wf0[4], acc0, 0, 0, 0);
        acc1 = __builtin_amdgcn_mfma_f32_16x16x32_bf16(__builtin_bit_cast(bf16x8, hv4), wf1[4], acc1, 0, 0, 0);
        acc0 = __builtin_amdgcn_mfma_f32_16x16x32_bf16(__builtin_bit_cast(bf16x8, hv5), wf0[5], acc0, 0, 0, 0);
        acc1 = __builtin_amdgcn_mfma_f32_16x16x32_bf16(__builtin_bit_cast(bf16x8, hv5), wf1[5], acc1, 0, 0, 0);
        acc0 = __builtin_amdgcn_mfma_f32_16x16x32_bf16(__builtin_bit_cast(bf16x8, hv6), wf0[6], acc0, 0, 0, 0);
        acc1 = __builtin_amdgcn_mfma_f32_16x16x32_bf16(__builtin_bit_cast(bf16x8, hv6), wf1[6], acc1, 0, 0, 0);
        acc0 = __builtin_amdgcn_mfma_f32_16x16x32_bf16(__builtin_bit_cast(bf16x8, hv7), wf0[7], acc0, 0, 0, 0);
        acc1 = __builtin_amdgcn_mfma_f32_16x16x32_bf16(__builtin_bit_cast(bf16x8, hv7), wf1[7], acc1, 0, 0, 0);

        // ---- wave-local gate transposes (2 tiles, no barrier) ----
        #pragma unroll
        for (int q = 0; q < 4; ++q) {
            trw0[(rb + q) * 17 + n_idx] = acc0[q];
            trw1[(rb + q) * 17 + n_idx] = acc1[q];
        }
        float g00 = trw0[er * 17 + hc * 4 + 0] + b00;
        float g01 = trw0[er * 17 + hc * 4 + 1] + b01;
        float g02 = trw0[er * 17 + hc * 4 + 2] + b02;
        float g03 = trw0[er * 17 + hc * 4 + 3] + b03;
        float g10 = trw1[er * 17 + hc * 4 + 0] + b10;
        float g11 = trw1[er * 17 + hc * 4 + 1] + b11;
        float g12 = trw1[er * 17 + hc * 4 + 2] + b12;
        float g13 = trw1[er * 17 + hc * 4 + 3] + b13;

        float i0 = sigm(g00), f0 = sigm(g01), gG0 = tanhfast(g02), o0 = sigm(g03);
        float i1 = sigm(g10), f1 = sigm(g11), gG1 = tanhfast(g12), o1 = sigm(g13);
        float c0 = f0 * creg0 + i0 * gG0; creg0 = c0;
        float c1 = f1 * creg1 + i1 * gG1; creg1 = c1;
        float h0 = o0 * tanhfast(c0);
        float h1 = o1 * tanhfast(c1);

        // ---- publish h (frag layout, sc0 sc1; 2 stores for hc-even lanes) ----
        unsigned hu0 = (unsigned)f2bf(h0);
        unsigned hu1 = (unsigned)f2bf(h1);
        unsigned pj0 = (unsigned)__shfl_xor((int)hu0, 16);
        unsigned pj1 = (unsigned)__shfl_xor((int)hu1, 16);
        if (!(lane & 16)) {
            unsigned v0 = hu0 | (pj0 << 16);
            unsigned v1 = hu1 | (pj1 << 16);
            asm volatile("global_store_dword %0, %1, off sc0 sc1" :: "v"(hw_base0 + wpar), "v"(v0) : "memory");
            asm volatile("global_store_dword %0, %1, off sc0 sc1" :: "v"(hw_base1 + wpar), "v"(v1) : "memory");
        }

        // ---- x_{t+1} prefetch under the store-ack window ----
        {
            const float* xp = xbase + (size_t)((t + 1 < T_SZ) ? t + 1 : t) * I_SZ;
            asm volatile("global_load_dwordx4 %0, %1, off" : "=v"(xa) : "v"(xp) : "memory");
            asm volatile("global_load_dwordx4 %0, %1, off" : "=v"(xb) : "v"(xp + 4) : "memory");
            asm volatile("global_load_dwordx4 %0, %1, off" : "=v"(xc) : "v"(xp + 32) : "memory");
            asm volatile("global_load_dwordx4 %0, %1, off" : "=v"(xd) : "v"(xp + 36) : "memory");
        }
        asm volatile("s_waitcnt vmcnt(4)" ::: "memory");   // both h-stores ack'd
        __builtin_amdgcn_s_barrier();                       // no counter drain
        if (tid == 0) {
            int fv = t + 1;
            asm volatile("global_store_dword %0, %1, off sc0 sc1" :: "v"(myflag), "v"(fv) : "memory");
        }
        asm volatile("s_waitcnt vmcnt(0)" ::: "memory");    // x loads done
        __builtin_amdgcn_sched_barrier(0);
        {
            unsigned p0, p1, p2, p3, p4, p5, p6, p7;
            asm("v_cvt_pk_bf16_f32 %0, %1, %2" : "=v"(p0) : "v"(xa[0]), "v"(xa[1]));
            asm("v_cvt_pk_bf16_f32 %0, %1, %2" : "=v"(p1) : "v"(xa[2]), "v"(xa[3]));
            asm("v_cvt_pk_bf16_f32 %0, %1, %2" : "=v"(p2) : "v"(xb[0]), "v"(xb[1]));
            asm("v_cvt_pk_bf16_f32 %0, %1, %2" : "=v"(p3) : "v"(xb[2]), "v"(xb[3]));
            asm("v_cvt_pk_bf16_f32 %0, %1, %2" : "=v"(p4) : "v"(xc[0]), "v"(xc[1]));
            asm("v_cvt_pk_bf16_f32 %0, %1, %2" : "=v"(p5) : "v"(xc[2]), "v"(xc[3]));
            asm("v_cvt_pk_bf16_f32 %0, %1, %2" : "=v"(p6) : "v"(xd[0]), "v"(xd[1]));
            asm("v_cvt_pk_bf16_f32 %0, %1, %2" : "=v"(p7) : "v"(xd[2]), "v"(xd[3]));
            xf0u = (u32x4){p0, p1, p2, p3};
            xf1u = (u32x4){p4, p5, p6, p7};
        }
    }

    // ---- heads (slice-0 blocks) ----
    if (ns == 0) {
        {
            int spin = 0;
            while (true) {
                int v;
                asm volatile("global_load_dword %0, %1, off sc0 sc1\n\t"
                             "s_waitcnt vmcnt(0)"
                             : "=v"(v) : "v"(fpoll) : "memory");
                if (__all(v >= T_SZ)) break;
                if (++spin > SPIN_CAP) break;
            }
            __builtin_amdgcn_sched_barrier(0);
        }
        // h_T is in parity (T_SZ & 1) = 0, frag layout; unpack to hstage
        {
            int kf = tid >> 6, l = tid & 63;
            const unsigned int* hp = hbuf + (size_t)bg * HB_GRP
                                     + kf * HB_FRG + l * 4;
            u32x4 hv;
            asm volatile("global_load_dwordx4 %0, %1, off sc0 sc1" : "=v"(hv) : "v"(hp) : "memory");
            asm volatile("s_waitcnt vmcnt(0)" ::: "memory");
            __builtin_amdgcn_sched_barrier(0);
            int row = l & 15;
            int cw = kf * 16 + (l >> 4) * 4;
            hstage[row * 128 + cw + 0] = hv[0];
            hstage[row * 128 + cw + 1] = hv[1];
            hstage[row * 128 + cw + 2] = hv[2];
            hstage[row * 128 + cw + 3] = hv[3];
        }
        __syncthreads();
        if (tid < MROWS * 8) {
            int r = tid >> 3, cc = tid & 7;
            const float* wrow;
            float bb;
            if (cc == 0)      { wrow = W_dir;                 bb = b_dir[0]; }
            else if (cc <= 5) { wrow = W_q + (cc - 1) * H_SZ; bb = b_q[cc - 1]; }
            else if (cc == 6) { wrow = W_rr;                  bb = b_rr[0]; }
            else              { wrow = W_sl;                  bb = b_sl[0]; }
            float s = bb;
            for (int k = 0; k < H_SZ; ++k) {
                unsigned u = hstage[r * 128 + (k >> 1)];
                unsigned short hs = (k & 1) ? (unsigned short)(u >> 16)
                                            : (unsigned short)(u & 0xFFFF);
                s += bf2f(hs) * wrow[k];
            }
            float v = (cc == 0) ? tanhfast(s) : (cc == 7) ? sigm(s) : s;
            out[(b0 + r) * 8 + cc] = v;
        }
    }
}

extern "C" void kernel_launch(void* const* d_in, const int* in_sizes, int n_in,
                              void* d_out, int out_size, void* d_ws, size_t ws_size,
                              hipStream_t stream) {
    const float* x     = (const float*)d_in[0];
    const float* W_ih  = (const float*)d_in[1];
    const float* W_hh  = (const float*)d_in[2];
    const float* b_ih  = (const float*)d_in[3];
    const float* b_hh  = (const float*)d_in[4];
    const float* W_dir = (const float*)d_in[5];
    const float* b_dir = (const float*)d_in[6];
    const float* W_q   = (const float*)d_in[7];
    const float* b_q   = (const float*)d_in[8];
    const float* W_rr  = (const float*)d_in[9];
    const float* b_rr  = (const float*)d_in[10];
    const float* W_sl  = (const float*)d_in[11];
    const float* b_sl  = (const float*)d_in[12];

    unsigned short* Wt = (unsigned short*)d_ws;
    float* bias        = (float*)((char*)d_ws + WS_BIAS_OFF);
    unsigned int* hbuf = (unsigned int*)((char*)d_ws + WS_HBUF_OFF);
    int* flags         = (int*)((char*)d_ws + WS_FLAGS_OFF);
    float* outp        = (float*)d_out;

    // 40960 frags + 1024 bias + 131072 hbuf + 8192 flags = 181248 = 708*256
    prep_kernel<<<708, 256, 0, stream>>>(W_ih, W_hh, b_ih, b_hh, Wt, bias,
                                         hbuf, flags);

    void* args[] = {(void*)&x, (void*)&Wt, (void*)&bias, (void*)&hbuf,
                    (void*)&flags, (void*)&W_dir, (void*)&b_dir, (void*)&W_q,
                    (void*)&b_q, (void*)&W_rr, (void*)&b_rr, (void*)&W_sl,
                    (void*)&b_sl, (void*)&outp};
    hipLaunchCooperativeKernel((void*)lstm_kernel, dim3(NBLK), dim3(NTHREADS),
                               args, 0, stream);
}